// Round 1
// baseline (7082.648 us; speedup 1.0000x reference)
//
#include <hip/hip_runtime.h>

// Problem constants (fixed by reference): T=32 enc + 32 dec, B=64, N=64, H=128
#define NB 64
#define NN 64
#define NH 128
#define K2 256  // 2*H

// ---------------------------------------------------------------------------
// Phase A: ru = sigmoid( S[b] @ (cat @ Wru) + bru ),  cat = [x, h]
//   cat@Wru decomposed: dense-x (Din=H) segment + h segment (+ rank-1 for Din=1)
//   grid = (4 col-chunks of 64, B) ; block = 256
// ---------------------------------------------------------------------------
__global__ __launch_bounds__(256) void cellA(
    const float* __restrict__ S, const float* __restrict__ x, int xdense,
    const float* __restrict__ hin, const float* __restrict__ W,
    const float* __restrict__ bias, float* __restrict__ ru)
{
  const int b = blockIdx.y;
  const int colBase = blockIdx.x * 64;
  const int tid = threadIdx.x;
  const int tx = tid & 15, ty = tid >> 4;
  const int c0 = tx * 4, r0 = ty * 4;

  __shared__ float As[16][68];   // [kk][node]  (A staged transposed)
  __shared__ float Bs[16][68];   // [kk][col]
  __shared__ float Us[64][68];   // U = cat@W chunk, staged for S@U
  __shared__ float Ss[64][68];   // S[b]

  float acc[4][4] = {{0.f}};

  const int nseg = xdense ? 2 : 1;
  for (int seg = 0; seg < nseg; ++seg) {
    const float* Ag = (xdense && seg == 0) ? (x + (size_t)b * NN * NH)
                                           : (hin + (size_t)b * NN * NH);
    const int wrow0 = xdense ? (seg == 0 ? 0 : NH) : 1;
    for (int k0 = 0; k0 < NH; k0 += 16) {
      #pragma unroll
      for (int e = 0; e < 4; ++e) {
        int idx = tid + e * 256;
        int n = idx >> 4, kk = idx & 15;
        As[kk][n] = Ag[(size_t)n * NH + k0 + kk];
      }
      #pragma unroll
      for (int e = 0; e < 4; ++e) {
        int idx = tid + e * 256;
        int kk = idx >> 6, c = idx & 63;
        Bs[kk][c] = W[(size_t)(wrow0 + k0 + kk) * K2 + colBase + c];
      }
      __syncthreads();
      #pragma unroll
      for (int kk = 0; kk < 16; ++kk) {
        float a[4], bb[4];
        #pragma unroll
        for (int i = 0; i < 4; ++i) a[i] = As[kk][r0 + i];
        #pragma unroll
        for (int j = 0; j < 4; ++j) bb[j] = Bs[kk][c0 + j];
        #pragma unroll
        for (int i = 0; i < 4; ++i)
          #pragma unroll
          for (int j = 0; j < 4; ++j) acc[i][j] += a[i] * bb[j];
      }
      __syncthreads();
    }
  }

  // rank-1 x-term for Din=1 cells (x may be null => zeros, decoder t=0)
  if (!xdense && x) {
    float wx[4], xv[4];
    #pragma unroll
    for (int j = 0; j < 4; ++j) wx[j] = W[colBase + c0 + j];  // W row 0
    #pragma unroll
    for (int i = 0; i < 4; ++i) xv[i] = x[(size_t)b * NN + r0 + i];
    #pragma unroll
    for (int i = 0; i < 4; ++i)
      #pragma unroll
      for (int j = 0; j < 4; ++j) acc[i][j] += xv[i] * wx[j];
  }

  // stage U and S[b], then P = S @ U
  #pragma unroll
  for (int i = 0; i < 4; ++i)
    #pragma unroll
    for (int j = 0; j < 4; ++j) Us[r0 + i][c0 + j] = acc[i][j];
  for (int e = 0; e < 16; ++e) {
    int idx = tid + e * 256;
    Ss[idx >> 6][idx & 63] = S[(size_t)b * NN * NN + idx];
  }
  __syncthreads();

  float p[4][4] = {{0.f}};
  for (int m = 0; m < 64; ++m) {
    float sv[4], uv[4];
    #pragma unroll
    for (int i = 0; i < 4; ++i) sv[i] = Ss[r0 + i][m];
    #pragma unroll
    for (int j = 0; j < 4; ++j) uv[j] = Us[m][c0 + j];
    #pragma unroll
    for (int i = 0; i < 4; ++i)
      #pragma unroll
      for (int j = 0; j < 4; ++j) p[i][j] += sv[i] * uv[j];
  }

  #pragma unroll
  for (int i = 0; i < 4; ++i) {
    int n = r0 + i;
    #pragma unroll
    for (int j = 0; j < 4; ++j) {
      int col = colBase + c0 + j;
      float v = p[i][j] + bias[col];
      ru[((size_t)b * NN + n) * K2 + col] = 1.f / (1.f + __expf(-v));
    }
  }
}

// ---------------------------------------------------------------------------
// Phase B: c = tanh( S[b] @ (cat2 @ Wc) + bc ), cat2 = [x, r*h]
//          hout = u*h + (1-u)*c
//   grid = (4 col-chunks of 32, B) ; block = 256
// ---------------------------------------------------------------------------
__global__ __launch_bounds__(256) void cellB(
    const float* __restrict__ S, const float* __restrict__ x, int xdense,
    const float* __restrict__ hin, const float* __restrict__ ru,
    const float* __restrict__ W, const float* __restrict__ bias,
    float* __restrict__ hout)
{
  const int b = blockIdx.y;
  const int colBase = blockIdx.x * 32;
  const int tid = threadIdx.x;
  const int tx = tid & 7, ty = tid >> 3;   // 8 x 32
  const int c0 = tx * 4, r0 = ty * 2;

  __shared__ float As[16][68];
  __shared__ float Bs[16][36];
  __shared__ float Vs[64][36];
  __shared__ float Ss[64][68];

  float acc[2][4] = {{0.f}};
  const int nseg = xdense ? 2 : 1;
  for (int seg = 0; seg < nseg; ++seg) {
    const bool isx = (xdense && seg == 0);
    const float* Ag = isx ? (x + (size_t)b * NN * NH) : nullptr;
    const int wrow0 = xdense ? (seg == 0 ? 0 : NH) : 1;
    for (int k0 = 0; k0 < NH; k0 += 16) {
      #pragma unroll
      for (int e = 0; e < 4; ++e) {
        int idx = tid + e * 256;
        int n = idx >> 4, kk = idx & 15;
        float av;
        if (isx) {
          av = Ag[(size_t)n * NH + k0 + kk];
        } else {
          size_t bn = (size_t)b * NN + n;
          av = ru[bn * K2 + k0 + kk] * hin[bn * NH + k0 + kk];  // r*h on load
        }
        As[kk][n] = av;
      }
      #pragma unroll
      for (int e = 0; e < 2; ++e) {
        int idx = tid + e * 256;
        int kk = idx >> 5, c = idx & 31;
        Bs[kk][c] = W[(size_t)(wrow0 + k0 + kk) * NH + colBase + c];
      }
      __syncthreads();
      #pragma unroll
      for (int kk = 0; kk < 16; ++kk) {
        float a0 = As[kk][r0], a1 = As[kk][r0 + 1];
        float bb[4];
        #pragma unroll
        for (int j = 0; j < 4; ++j) bb[j] = Bs[kk][c0 + j];
        #pragma unroll
        for (int j = 0; j < 4; ++j) { acc[0][j] += a0 * bb[j]; acc[1][j] += a1 * bb[j]; }
      }
      __syncthreads();
    }
  }

  if (!xdense && x) {
    float wx[4];
    #pragma unroll
    for (int j = 0; j < 4; ++j) wx[j] = W[colBase + c0 + j];  // W row 0
    #pragma unroll
    for (int i = 0; i < 2; ++i) {
      float xv = x[(size_t)b * NN + r0 + i];
      #pragma unroll
      for (int j = 0; j < 4; ++j) acc[i][j] += xv * wx[j];
    }
  }

  #pragma unroll
  for (int i = 0; i < 2; ++i)
    #pragma unroll
    for (int j = 0; j < 4; ++j) Vs[r0 + i][c0 + j] = acc[i][j];
  for (int e = 0; e < 16; ++e) {
    int idx = tid + e * 256;
    Ss[idx >> 6][idx & 63] = S[(size_t)b * NN * NN + idx];
  }
  __syncthreads();

  float p[2][4] = {{0.f}};
  for (int m = 0; m < 64; ++m) {
    float s0 = Ss[r0][m], s1 = Ss[r0 + 1][m];
    float vv[4];
    #pragma unroll
    for (int j = 0; j < 4; ++j) vv[j] = Vs[m][c0 + j];
    #pragma unroll
    for (int j = 0; j < 4; ++j) { p[0][j] += s0 * vv[j]; p[1][j] += s1 * vv[j]; }
  }

  #pragma unroll
  for (int i = 0; i < 2; ++i) {
    int n = r0 + i;
    size_t bn = (size_t)b * NN + n;
    #pragma unroll
    for (int j = 0; j < 4; ++j) {
      int col = colBase + c0 + j;
      float c = tanhf(p[i][j] + bias[col]);
      float u = ru[bn * K2 + NH + col];
      float hv = hin[bn * NH + col];
      hout[bn * NH + col] = u * hv + (1.f - u) * c;
    }
  }
}

// proj[b,n] = h1[b,n,:] . Wp + bp   (one wave per (b,n))
__global__ __launch_bounds__(256) void projk(
    const float* __restrict__ h1, const float* __restrict__ Wp,
    const float* __restrict__ bp, float* __restrict__ out)
{
  int wave = threadIdx.x >> 6, lane = threadIdx.x & 63;
  int bn = blockIdx.x * 4 + wave;  // 0..4095
  const float* hp = h1 + (size_t)bn * NH;
  float s = hp[lane] * Wp[lane] + hp[lane + 64] * Wp[lane + 64];
  #pragma unroll
  for (int off = 32; off; off >>= 1) s += __shfl_down(s, off);
  if (lane == 0) out[bn] = s + bp[0];
}

__global__ void zerok(float* __restrict__ p, int n)
{
  int i = blockIdx.x * blockDim.x + threadIdx.x;
  if (i < n) p[i] = 0.f;
}

// ---------------------------------------------------------------------------
extern "C" void kernel_launch(void* const* d_in, const int* in_sizes, int n_in,
                              void* d_out, int out_size, void* d_ws, size_t ws_size,
                              hipStream_t stream)
{
  const float* inp = (const float*)d_in[0];   // [32,B,N] (Din=1)
  const float* S   = (const float*)d_in[2];   // [B,N,N]
  const float* w[16];
  for (int i = 0; i < 16; ++i) w[i] = (const float*)d_in[3 + i];
  // w: e0{Wru,bru,Wc,bc} e1{...} d0{...} db{...}
  const float* Wp = (const float*)d_in[19];
  const float* bp = (const float*)d_in[20];
  float* out = (float*)d_out;                 // [32,B,N]
  float* ws = (float*)d_ws;

  const size_t BNH = (size_t)NB * NN * NH;    // 524288
  float* st0[2] = { ws,            ws + BNH };
  float* st1[2] = { ws + 2 * BNH,  ws + 3 * BNH };
  float* ru0 = ws + 4 * BNH;                  // [B,N,2H]
  float* ru1 = ws + 6 * BNH;

  // zero-init both parities of both states (ws is poisoned each call)
  {
    int n = (int)(4 * BNH);
    zerok<<<(n + 255) / 256, 256, 0, stream>>>(ws, n);
  }

  dim3 gA(4, NB), gB(4, NB);

  // ---- encoder: layers computed step-wise (no hs0 materialization) ----
  for (int t = 0; t < 32; ++t) {
    const float* x = inp + (size_t)t * NB * NN;
    int pi = t & 1, po = (t + 1) & 1;
    cellA<<<gA, 256, 0, stream>>>(S, x, 0, st0[pi], w[0], w[1], ru0);
    cellB<<<gB, 256, 0, stream>>>(S, x, 0, st0[pi], ru0, w[2], w[3], st0[po]);
    cellA<<<gA, 256, 0, stream>>>(S, st0[po], 1, st1[pi], w[4], w[5], ru1);
    cellB<<<gB, 256, 0, stream>>>(S, st0[po], 1, st1[pi], ru1, w[6], w[7], st1[po]);
  }

  // ---- decoder: strictly sequential (proj feeds back) ----
  for (int t = 0; t < 32; ++t) {
    const float* x = t ? (out + (size_t)(t - 1) * NB * NN) : nullptr;  // go = 0
    int pi = t & 1, po = (t + 1) & 1;
    cellA<<<gA, 256, 0, stream>>>(S, x, 0, st0[pi], w[8],  w[9],  ru0);
    cellB<<<gB, 256, 0, stream>>>(S, x, 0, st0[pi], ru0, w[10], w[11], st0[po]);
    cellA<<<gA, 256, 0, stream>>>(S, st0[po], 1, st1[pi], w[12], w[13], ru1);
    cellB<<<gB, 256, 0, stream>>>(S, st0[po], 1, st1[pi], ru1, w[14], w[15], st1[po]);
    projk<<<1024, 256, 0, stream>>>(st1[po], Wp, bp, out + (size_t)t * NB * NN);
  }
}